// Round 16
// baseline (191.683 us; speedup 1.0000x reference)
//
#include <hip/hip_runtime.h>

// GraphSAGE (pool aggregator), 2 layers + linear head.
// N=100000, E=1600000, IN=128, H=64, C=2.
// GEMMs: bf16 MFMA (16x16x32), weights split W_hi+W_lo (two MFMA passes).
// Front: 512-thread blocks — scatter (SCHUNK=8192) + pool1 GEMM. Scatter
// reservations padded to 64B lines (one owner block per line -> no cross-XCD
// write-RMW bouncing); pad filled with sentinel words the agg kernels skip.
// Aggregation: per-bin counting sort + 4-deep register max. Layer 1 dual
// GEMM + in-LDS pool2; layer 2 agg fused with dual GEMM + head.
// All maxes order-invariant -> deterministic output.

#define BIN_CAP 4864
#define MAX_BINS 1024
#define SCHUNK 8192
#define SENTINEL 0xFFFFFFFFu

typedef __attribute__((ext_vector_type(8))) short bf16x8;
typedef __attribute__((ext_vector_type(4))) float f32x4;

union FU { uint4 u; bf16x8 v; };

__device__ __forceinline__ unsigned bf16rne(float f) {
  const unsigned u = __float_as_uint(f);
  return (u + 0x7FFFu + ((u >> 16) & 1u)) >> 16;
}

__device__ __forceinline__ unsigned umax_(unsigned a, unsigned b) {
  return a > b ? a : b;
}

// ---------------- weight pack: fragment-ordered W_hi / W_lo ----------------
__global__ __launch_bounds__(64) void pack_w(
    const float* __restrict__ Wp1, const float* __restrict__ Ws1,
    const float* __restrict__ Wn1, const float* __restrict__ Wp2,
    const float* __restrict__ Ws2, const float* __restrict__ Wn2,
    unsigned* __restrict__ packW) {
  const int b = blockIdx.x, l = threadIdx.x;
  const float* W; int N, base, fi;
  if (b < 32)      { W = Wp1; N = 128; base = 0;  fi = b; }
  else if (b < 48) { W = Ws1; N = 64;  base = 32; fi = b - 32; }
  else if (b < 64) { W = Wn1; N = 64;  base = 48; fi = b - 48; }
  else if (b < 72) { W = Wp2; N = 64;  base = 64; fi = b - 64; }
  else if (b < 80) { W = Ws2; N = 64;  base = 72; fi = b - 72; }
  else             { W = Wn2; N = 64;  base = 80; fi = b - 80; }
  const int NT = N / 16;
  const int ks = fi / NT, nt = fi % NT;
  const int col = nt * 16 + (l & 15);
  unsigned hs[8], ls[8];
#pragma unroll
  for (int i = 0; i < 8; ++i) {
    const int k = ks * 32 + (l >> 4) * 8 + i;
    const float w = W[(size_t)k * N + col];
    const unsigned h = bf16rne(w);
    const float r = w - __uint_as_float(h << 16);
    hs[i] = h; ls[i] = bf16rne(r);
  }
  uint4 hw, lw;
  hw.x = hs[0] | (hs[1] << 16); hw.y = hs[2] | (hs[3] << 16);
  hw.z = hs[4] | (hs[5] << 16); hw.w = hs[6] | (hs[7] << 16);
  lw.x = ls[0] | (ls[1] << 16); lw.y = ls[2] | (ls[3] << 16);
  lw.z = ls[4] | (ls[5] << 16); lw.w = ls[6] | (ls[7] << 16);
  unsigned* p = packW + (size_t)(base + fi) * 512 + l * 4;
  *(uint4*)p = hw;
  *(uint4*)(p + 256) = lw;
}

// ---------------- 2-row MFMA pass (256-thread GEMMs) ----------------
template <int DIN, int DOUT, bool AF32>
__device__ __forceinline__ void mfma_pass(
    const void* __restrict__ P, const unsigned* __restrict__ packW,
    int fragBase, int ra0, int ra1, int l, f32x4* acc0, f32x4* acc1) {
  constexpr int KS = DIN / 32, NT = DOUT / 16;
  const int lk = l >> 4;
#pragma unroll
  for (int ks = 0; ks < KS; ++ks) {
    FU a0, a1;
    if (AF32) {
      const float* p0 = (const float*)P + (size_t)ra0 * DIN + ks * 32 + lk * 8;
      const float* p1 = (const float*)P + (size_t)ra1 * DIN + ks * 32 + lk * 8;
      const float4 f00 = *(const float4*)p0, f01 = *(const float4*)(p0 + 4);
      const float4 f10 = *(const float4*)p1, f11 = *(const float4*)(p1 + 4);
      a0.u.x = bf16rne(f00.x) | (bf16rne(f00.y) << 16);
      a0.u.y = bf16rne(f00.z) | (bf16rne(f00.w) << 16);
      a0.u.z = bf16rne(f01.x) | (bf16rne(f01.y) << 16);
      a0.u.w = bf16rne(f01.z) | (bf16rne(f01.w) << 16);
      a1.u.x = bf16rne(f10.x) | (bf16rne(f10.y) << 16);
      a1.u.y = bf16rne(f10.z) | (bf16rne(f10.w) << 16);
      a1.u.z = bf16rne(f11.x) | (bf16rne(f11.y) << 16);
      a1.u.w = bf16rne(f11.z) | (bf16rne(f11.w) << 16);
    } else {
      a0.u = *(const uint4*)((const unsigned*)P + (size_t)ra0 * (DIN / 2) + ks * 16 + lk * 4);
      a1.u = *(const uint4*)((const unsigned*)P + (size_t)ra1 * (DIN / 2) + ks * 16 + lk * 4);
    }
#pragma unroll
    for (int nt = 0; nt < NT; ++nt) {
      const unsigned* bp = packW + (size_t)(fragBase + ks * NT + nt) * 512 + l * 4;
      FU bh, bl_;
      bh.u = *(const uint4*)bp;
      bl_.u = *(const uint4*)(bp + 256);
      acc0[nt] = __builtin_amdgcn_mfma_f32_16x16x32_bf16(a0.v, bh.v, acc0[nt], 0, 0, 0);
      acc1[nt] = __builtin_amdgcn_mfma_f32_16x16x32_bf16(a1.v, bh.v, acc1[nt], 0, 0, 0);
      acc0[nt] = __builtin_amdgcn_mfma_f32_16x16x32_bf16(a0.v, bl_.v, acc0[nt], 0, 0, 0);
      acc1[nt] = __builtin_amdgcn_mfma_f32_16x16x32_bf16(a1.v, bl_.v, acc1[nt], 0, 0, 0);
    }
  }
}

// pool1 body, 512 threads: 8 waves x 16 rows; out = relu(x@Wp1+b) packed bf16.
__device__ __forceinline__ void pool1_body512(
    int bid, int tid, const float* __restrict__ x,
    const unsigned* __restrict__ packW, const float* __restrict__ bias,
    unsigned* __restrict__ out, int n) {
  const int wv = tid >> 6, l = tid & 63;
  const int lrow = l & 15, lk = l >> 4;
  const int r0 = bid * 128 + wv * 16;
  int ra = r0 + lrow; if (ra >= n) ra = n - 1;
  f32x4 acc[8];
#pragma unroll
  for (int i = 0; i < 8; ++i) acc[i] = f32x4{0.f, 0.f, 0.f, 0.f};
#pragma unroll
  for (int ks = 0; ks < 4; ++ks) {
    FU a;
    const float* p = x + (size_t)ra * 128 + ks * 32 + lk * 8;
    const float4 f0 = *(const float4*)p, f1 = *(const float4*)(p + 4);
    a.u.x = bf16rne(f0.x) | (bf16rne(f0.y) << 16);
    a.u.y = bf16rne(f0.z) | (bf16rne(f0.w) << 16);
    a.u.z = bf16rne(f1.x) | (bf16rne(f1.y) << 16);
    a.u.w = bf16rne(f1.z) | (bf16rne(f1.w) << 16);
#pragma unroll
    for (int nt = 0; nt < 8; ++nt) {
      const unsigned* bp = packW + (size_t)(ks * 8 + nt) * 512 + l * 4;
      FU bh, bl_;
      bh.u = *(const uint4*)bp;
      bl_.u = *(const uint4*)(bp + 256);
      acc[nt] = __builtin_amdgcn_mfma_f32_16x16x32_bf16(a.v, bh.v, acc[nt], 0, 0, 0);
      acc[nt] = __builtin_amdgcn_mfma_f32_16x16x32_bf16(a.v, bl_.v, acc[nt], 0, 0, 0);
    }
  }
#pragma unroll
  for (int nt = 0; nt < 8; ++nt) {
    const float bv = bias[nt * 16 + lrow];
#pragma unroll
    for (int i = 0; i < 4; ++i) {
      float v = fmaxf(acc[nt][i] + bv, 0.f);
      const float vo = __shfl_xor(v, 1);
      const int row = r0 + lk * 4 + i;
      if (!(l & 1) && row < n)
        out[(size_t)row * 64 + nt * 8 + (lrow >> 1)] =
            bf16rne(v) | (bf16rne(vo) << 16);
    }
  }
}

// ------- scatter body (512 threads): line-padded per-(block,bin) runs ------
__device__ __forceinline__ void scatter_body512(
    int bid, int t, int* hist, int* base,
    const int* __restrict__ src, const int* __restrict__ dst,
    unsigned* __restrict__ binCursor, unsigned* __restrict__ ebuf,
    int nE, int nb) {
  const int blockBase = bid * SCHUNK;
  for (int i = t; i < nb; i += 512) hist[i] = 0;
  __syncthreads();
  const int lim = (nE - blockBase < SCHUNK) ? (nE - blockBase) : SCHUNK;
  const int* dp = dst + blockBase;
  const int* sp = src + blockBase;
  const int nv = lim >> 2;
  for (int v = t; v < nv; v += 512) {
    const int4 d4 = *(const int4*)(dp + v * 4);
    atomicAdd(&hist[d4.x >> 7], 1);
    atomicAdd(&hist[d4.y >> 7], 1);
    atomicAdd(&hist[d4.z >> 7], 1);
    atomicAdd(&hist[d4.w >> 7], 1);
  }
  for (int i = (nv << 2) + t; i < lim; i += 512)
    atomicAdd(&hist[dp[i] >> 7], 1);
  __syncthreads();
  // Reserve a LINE-PADDED region per bin (16-word multiple). ebuf bin bases
  // are 16KB-aligned, so every 64B line is written by exactly one block.
  for (int i = t; i < nb; i += 512) {
    const int c = hist[i];
    int pb = 0;
    if (c) {
      const int padded = (c + 15) & ~15;
      pb = (int)atomicAdd(&binCursor[i], (unsigned)padded);
      unsigned* bp = ebuf + (size_t)i * BIN_CAP;
      for (int p = c; p < padded; ++p) {
        const unsigned pos = (unsigned)(pb + p);
        if (pos < BIN_CAP) bp[pos] = SENTINEL;
      }
    }
    base[i] = pb;
    hist[i] = 0;
  }
  __syncthreads();
  for (int v = t; v < nv; v += 512) {
    const int4 d4 = *(const int4*)(dp + v * 4);
    const int4 s4 = *(const int4*)(sp + v * 4);
    const int dd[4] = {d4.x, d4.y, d4.z, d4.w};
    const int ss[4] = {s4.x, s4.y, s4.z, s4.w};
#pragma unroll
    for (int q = 0; q < 4; ++q) {
      const int bin = dd[q] >> 7;
      const int loc = atomicAdd(&hist[bin], 1);
      const unsigned pos = (unsigned)base[bin] + (unsigned)loc;
      if (pos < BIN_CAP)
        ebuf[(size_t)bin * BIN_CAP + pos] =
            ((unsigned)ss[q] << 7) | (unsigned)(dd[q] & 127);
    }
  }
  for (int i = (nv << 2) + t; i < lim; i += 512) {
    const int d = dp[i];
    const int bin = d >> 7;
    const int loc = atomicAdd(&hist[bin], 1);
    const unsigned pos = (unsigned)base[bin] + (unsigned)loc;
    if (pos < BIN_CAP)
      ebuf[(size_t)bin * BIN_CAP + pos] = ((unsigned)sp[i] << 7) | (unsigned)(d & 127);
  }
}

// ---------------- fused front (512 threads): scatter + pool1 GEMM ----------
__global__ __launch_bounds__(512) void fused_front(
    const int* __restrict__ src, const int* __restrict__ dst,
    unsigned* __restrict__ binCursor, unsigned* __restrict__ ebuf,
    int nE, int nb, int nsb,
    const float* __restrict__ x, const unsigned* __restrict__ packW,
    const float* __restrict__ bias, unsigned* __restrict__ pooled1, int n) {
  __shared__ int hist[MAX_BINS];
  __shared__ int base[MAX_BINS];
  if ((int)blockIdx.x < nsb) {
    scatter_body512(blockIdx.x, threadIdx.x, hist, base,
                    src, dst, binCursor, ebuf, nE, nb);
  } else {
    pool1_body512(blockIdx.x - nsb, threadIdx.x, x, packW, bias, pooled1, n);
  }
}

// ---------------- agg_sort: counting sort (sentinel-skip) + register max ---
template <int POOLW>
__global__ __launch_bounds__(512) void agg_sort(
    const unsigned* __restrict__ ebuf, const unsigned* __restrict__ binCnt,
    const unsigned* __restrict__ pooled, unsigned* __restrict__ agg, int n) {
  __shared__ unsigned sorted[BIN_CAP];
  __shared__ int hist[128];
  __shared__ int scan_[128];
  __shared__ int startv[129];
  __shared__ int cursor[128];
  const int b = blockIdx.x;
  const int t = threadIdx.x;
  unsigned cnt = binCnt[b]; if (cnt > BIN_CAP) cnt = BIN_CAP;
  if (t < 128) hist[t] = 0;
  __syncthreads();
  const unsigned* eb = ebuf + (size_t)b * BIN_CAP;
  for (unsigned i = t; i < cnt; i += 512) {
    const unsigned w = eb[i];
    if (w != SENTINEL) atomicAdd(&hist[w & 127u], 1);
  }
  __syncthreads();
  if (t < 128) scan_[t] = hist[t];
  __syncthreads();
#pragma unroll
  for (int ofs = 1; ofs < 128; ofs <<= 1) {
    int v = 0;
    if (t < 128 && t >= ofs) v = scan_[t - ofs];
    __syncthreads();
    if (t < 128) scan_[t] += v;
    __syncthreads();
  }
  if (t < 128) {
    const int s = scan_[t] - hist[t];
    startv[t] = s;
    cursor[t] = s;
    if (t == 127) startv[128] = scan_[127];
  }
  __syncthreads();
  for (unsigned i = t; i < cnt; i += 512) {
    const unsigned w = eb[i];
    if (w != SENTINEL)
      sorted[atomicAdd(&cursor[w & 127u], 1)] = w >> 7;
  }
  __syncthreads();
  constexpr int LW = (POOLW == 64) ? 64 : 32;
  constexpr int NPROC = 512 / LW;
  const int proc = t / LW;
  const int lw = t % LW;
  const int base = b << 7;
  for (int local = proc; local < 128; local += NPROC) {
    const int node = base + local;
    if (node >= n) continue;
    const int s0 = startv[local], s1 = startv[local + 1];
    unsigned me = 0u, mo = 0u;
    int j = s0;
    for (; j + 4 <= s1; j += 4) {
      const unsigned a0 = sorted[j],     a1 = sorted[j + 1];
      const unsigned a2 = sorted[j + 2], a3 = sorted[j + 3];
      const unsigned v0 = pooled[(size_t)a0 * POOLW + lw];
      const unsigned v1 = pooled[(size_t)a1 * POOLW + lw];
      const unsigned v2 = pooled[(size_t)a2 * POOLW + lw];
      const unsigned v3 = pooled[(size_t)a3 * POOLW + lw];
      me = umax_(umax_(me, v0 << 16),
                 umax_(v1 << 16, umax_(v2 << 16, v3 << 16)));
      mo = umax_(umax_(mo, v0 & 0xFFFF0000u),
                 umax_(v1 & 0xFFFF0000u,
                       umax_(v2 & 0xFFFF0000u, v3 & 0xFFFF0000u)));
    }
    for (; j < s1; ++j) {
      const unsigned v = pooled[(size_t)sorted[j] * POOLW + lw];
      me = umax_(me, v << 16);
      mo = umax_(mo, v & 0xFFFF0000u);
    }
    agg[(size_t)node * POOLW + lw] = (me >> 16) | (mo & 0xFFFF0000u);
  }
}

// ---------------- dual GEMM layer1 + fused pool2 ----------------
__global__ __launch_bounds__(256) void gemm_dual1_pool2(
    const float* __restrict__ x, const unsigned* __restrict__ agg1,
    const unsigned* __restrict__ packW, const float* __restrict__ b1,
    const float* __restrict__ bp2, unsigned* __restrict__ h1,
    unsigned* __restrict__ pooled2, int n) {
  __shared__ unsigned h1s[128 * 36];
  const int t = threadIdx.x;
  const int wave = t >> 6, l = t & 63;
  const int lrow = l & 15, lk = l >> 4;
  const int lr0 = wave * 32;
  const int r0 = blockIdx.x * 128 + lr0;
  int ra0 = r0 + lrow;      if (ra0 >= n) ra0 = n - 1;
  int ra1 = r0 + 16 + lrow; if (ra1 >= n) ra1 = n - 1;
  f32x4 acc0[4], acc1[4];
#pragma unroll
  for (int i = 0; i < 4; ++i) {
    acc0[i] = f32x4{0.f, 0.f, 0.f, 0.f};
    acc1[i] = f32x4{0.f, 0.f, 0.f, 0.f};
  }
  mfma_pass<128, 64, true>(x, packW, 32, ra0, ra1, l, acc0, acc1);
  mfma_pass<128, 64, false>(agg1, packW, 48, ra0, ra1, l, acc0, acc1);
#pragma unroll
  for (int nt = 0; nt < 4; ++nt) {
    const float bv = b1[nt * 16 + lrow];
#pragma unroll
    for (int j = 0; j < 2; ++j) {
      const f32x4 a = j ? acc1[nt] : acc0[nt];
#pragma unroll
      for (int i = 0; i < 4; ++i) {
        float v = fmaxf(a[i] + bv, 0.f);
        const float vo = __shfl_xor(v, 1);
        if (!(l & 1)) {
          const int rl = lr0 + j * 16 + lk * 4 + i;
          const unsigned w = bf16rne(v) | (bf16rne(vo) << 16);
          h1s[rl * 36 + nt * 8 + (lrow >> 1)] = w;
          const int row = blockIdx.x * 128 + rl;
          if (row < n) h1[(size_t)row * 32 + nt * 8 + (lrow >> 1)] = w;
        }
      }
    }
  }
  __syncthreads();
#pragma unroll
  for (int i = 0; i < 4; ++i) {
    acc0[i] = f32x4{0.f, 0.f, 0.f, 0.f};
    acc1[i] = f32x4{0.f, 0.f, 0.f, 0.f};
  }
#pragma unroll
  for (int ks = 0; ks < 2; ++ks) {
    FU a0, a1;
    a0.u = *(const uint4*)&h1s[(lr0 + lrow) * 36 + ks * 16 + lk * 4];
    a1.u = *(const uint4*)&h1s[(lr0 + 16 + lrow) * 36 + ks * 16 + lk * 4];
#pragma unroll
    for (int nt = 0; nt < 4; ++nt) {
      const unsigned* bp = packW + (size_t)(64 + ks * 4 + nt) * 512 + l * 4;
      FU bh, bl_;
      bh.u = *(const uint4*)bp;
      bl_.u = *(const uint4*)(bp + 256);
      acc0[nt] = __builtin_amdgcn_mfma_f32_16x16x32_bf16(a0.v, bh.v, acc0[nt], 0, 0, 0);
      acc1[nt] = __builtin_amdgcn_mfma_f32_16x16x32_bf16(a1.v, bh.v, acc1[nt], 0, 0, 0);
      acc0[nt] = __builtin_amdgcn_mfma_f32_16x16x32_bf16(a0.v, bl_.v, acc0[nt], 0, 0, 0);
      acc1[nt] = __builtin_amdgcn_mfma_f32_16x16x32_bf16(a1.v, bl_.v, acc1[nt], 0, 0, 0);
    }
  }
#pragma unroll
  for (int nt = 0; nt < 4; ++nt) {
    const float bv = bp2[nt * 16 + lrow];
#pragma unroll
    for (int j = 0; j < 2; ++j) {
      const f32x4 a = j ? acc1[nt] : acc0[nt];
#pragma unroll
      for (int i = 0; i < 4; ++i) {
        float v = fmaxf(a[i] + bv, 0.f);
        const float vo = __shfl_xor(v, 1);
        const int row = r0 + j * 16 + lk * 4 + i;
        if (!(l & 1) && row < n)
          pooled2[(size_t)row * 32 + nt * 8 + (lrow >> 1)] =
              bf16rne(v) | (bf16rne(vo) << 16);
      }
    }
  }
}

// ---------------- fused per-bin aggregation + GEMM + head (layer 2) --------
template <int POOLW, int DIN, int FB0, int FB1>
__global__ __launch_bounds__(512) void agg_gemm_head(
    const unsigned* __restrict__ ebuf, const unsigned* __restrict__ binCnt,
    const unsigned* __restrict__ pooled, const unsigned* __restrict__ A,
    const unsigned* __restrict__ packW, const float* __restrict__ bias,
    const float* __restrict__ Wout, const float* __restrict__ bout,
    float* __restrict__ outf, int n) {
  constexpr int STR = POOLW + 4;
  __shared__ unsigned sorted[BIN_CAP];
  __shared__ int hist[128];
  __shared__ int scan_[128];
  __shared__ int startv[129];
  __shared__ int cursor[128];
  __shared__ unsigned agg_lds[128 * STR];
  const int b = blockIdx.x;
  const int t = threadIdx.x;
  unsigned cnt = binCnt[b]; if (cnt > BIN_CAP) cnt = BIN_CAP;
  if (t < 128) hist[t] = 0;
  __syncthreads();
  const unsigned* eb = ebuf + (size_t)b * BIN_CAP;
  for (unsigned i = t; i < cnt; i += 512) {
    const unsigned w = eb[i];
    if (w != SENTINEL) atomicAdd(&hist[w & 127u], 1);
  }
  __syncthreads();
  if (t < 128) scan_[t] = hist[t];
  __syncthreads();
#pragma unroll
  for (int ofs = 1; ofs < 128; ofs <<= 1) {
    int v = 0;
    if (t < 128 && t >= ofs) v = scan_[t - ofs];
    __syncthreads();
    if (t < 128) scan_[t] += v;
    __syncthreads();
  }
  if (t < 128) {
    const int s = scan_[t] - hist[t];
    startv[t] = s;
    cursor[t] = s;
    if (t == 127) startv[128] = scan_[127];
  }
  __syncthreads();
  for (unsigned i = t; i < cnt; i += 512) {
    const unsigned w = eb[i];
    if (w != SENTINEL)
      sorted[atomicAdd(&cursor[w & 127u], 1)] = w >> 7;
  }
  __syncthreads();
  {
    constexpr int LW = 32;
    constexpr int NPROC = 512 / LW;
    const int proc = t / LW, lw = t % LW;
    for (int local = proc; local < 128; local += NPROC) {
      const int s0 = startv[local], s1 = startv[local + 1];
      unsigned me = 0u, mo = 0u;
      int j = s0;
      for (; j + 4 <= s1; j += 4) {
        const unsigned a0 = sorted[j],     a1 = sorted[j + 1];
        const unsigned a2 = sorted[j + 2], a3 = sorted[j + 3];
        const unsigned v0 = pooled[(size_t)a0 * POOLW + lw];
        const unsigned v1 = pooled[(size_t)a1 * POOLW + lw];
        const unsigned v2 = pooled[(size_t)a2 * POOLW + lw];
        const unsigned v3 = pooled[(size_t)a3 * POOLW + lw];
        me = umax_(umax_(me, v0 << 16),
                   umax_(v1 << 16, umax_(v2 << 16, v3 << 16)));
        mo = umax_(umax_(mo, v0 & 0xFFFF0000u),
                   umax_(v1 & 0xFFFF0000u,
                         umax_(v2 & 0xFFFF0000u, v3 & 0xFFFF0000u)));
      }
      for (; j < s1; ++j) {
        const unsigned v = pooled[(size_t)sorted[j] * POOLW + lw];
        me = umax_(me, v << 16);
        mo = umax_(mo, v & 0xFFFF0000u);
      }
      agg_lds[local * STR + lw] = (me >> 16) | (mo & 0xFFFF0000u);
    }
  }
  __syncthreads();
  constexpr int KS = DIN / 32, NT = 4;
  const int wv = t >> 6, l = t & 63;
  const int lrow = l & 15, lk = l >> 4;
  const int lr = wv * 16 + lrow;
  const int r0 = b * 128 + wv * 16;
  int ra = r0 + lrow; if (ra >= n) ra = n - 1;
  f32x4 acc[NT];
#pragma unroll
  for (int i = 0; i < NT; ++i) acc[i] = f32x4{0.f, 0.f, 0.f, 0.f};
#pragma unroll
  for (int ks = 0; ks < KS; ++ks) {
    FU a;
    a.u = *(const uint4*)(A + (size_t)ra * (DIN / 2) + ks * 16 + lk * 4);
#pragma unroll
    for (int nt = 0; nt < NT; ++nt) {
      const unsigned* bp = packW + (size_t)(FB0 + ks * NT + nt) * 512 + l * 4;
      FU bh, bl_;
      bh.u = *(const uint4*)bp;
      bl_.u = *(const uint4*)(bp + 256);
      acc[nt] = __builtin_amdgcn_mfma_f32_16x16x32_bf16(a.v, bh.v, acc[nt], 0, 0, 0);
      acc[nt] = __builtin_amdgcn_mfma_f32_16x16x32_bf16(a.v, bl_.v, acc[nt], 0, 0, 0);
    }
  }
#pragma unroll
  for (int ks = 0; ks < KS; ++ks) {
    FU a;
    a.u = *(const uint4*)&agg_lds[lr * STR + ks * 16 + lk * 4];
#pragma unroll
    for (int nt = 0; nt < NT; ++nt) {
      const unsigned* bp = packW + (size_t)(FB1 + ks * NT + nt) * 512 + l * 4;
      FU bh, bl_;
      bh.u = *(const uint4*)bp;
      bl_.u = *(const uint4*)(bp + 256);
      acc[nt] = __builtin_amdgcn_mfma_f32_16x16x32_bf16(a.v, bh.v, acc[nt], 0, 0, 0);
      acc[nt] = __builtin_amdgcn_mfma_f32_16x16x32_bf16(a.v, bl_.v, acc[nt], 0, 0, 0);
    }
  }
  float p0[4] = {0.f, 0.f, 0.f, 0.f}, p1[4] = {0.f, 0.f, 0.f, 0.f};
#pragma unroll
  for (int nt = 0; nt < NT; ++nt) {
    const float bv = bias[nt * 16 + lrow];
    const int c = nt * 16 + lrow;
    const float w0 = Wout[c * 2 + 0], w1 = Wout[c * 2 + 1];
#pragma unroll
    for (int i = 0; i < 4; ++i) {
      const float v = fmaxf(acc[nt][i] + bv, 0.f);
      p0[i] = fmaf(v, w0, p0[i]);
      p1[i] = fmaf(v, w1, p1[i]);
    }
  }
#pragma unroll
  for (int m = 1; m < 16; m <<= 1) {
#pragma unroll
    for (int i = 0; i < 4; ++i) {
      p0[i] += __shfl_xor(p0[i], m);
      p1[i] += __shfl_xor(p1[i], m);
    }
  }
  if (lrow == 0) {
    const float b0 = bout[0], b1v = bout[1];
#pragma unroll
    for (int i = 0; i < 4; ++i) {
      const int row = r0 + lk * 4 + i;
      if (row < n) {
        float2 o; o.x = p0[i] + b0; o.y = p1[i] + b1v;
        *(float2*)(outf + (size_t)row * 2) = o;
      }
    }
  }
}

extern "C" void kernel_launch(void* const* d_in, const int* in_sizes, int n_in,
                              void* d_out, int out_size, void* d_ws, size_t ws_size,
                              hipStream_t stream) {
  const float* x       = (const float*)d_in[0];
  const int*   src     = (const int*)d_in[1];
  const int*   dst     = (const int*)d_in[2];
  const float* W_pool1 = (const float*)d_in[3];
  const float* b_pool1 = (const float*)d_in[4];
  const float* W_self1 = (const float*)d_in[5];
  const float* W_neigh1= (const float*)d_in[6];
  const float* b1      = (const float*)d_in[7];
  const float* W_pool2 = (const float*)d_in[8];
  const float* b_pool2 = (const float*)d_in[9];
  const float* W_self2 = (const float*)d_in[10];
  const float* W_neigh2= (const float*)d_in[11];
  const float* b2      = (const float*)d_in[12];
  const float* W_out   = (const float*)d_in[13];
  const float* b_out   = (const float*)d_in[14];

  const int n  = in_sizes[0] / 128;
  const int nE = in_sizes[1];
  const int NB = (n + 127) >> 7;
  const int NSB = (nE + SCHUNK - 1) / SCHUNK;
  const int GG = (n + 127) / 128;

  // workspace (u32 units):
  unsigned* pooled1 = (unsigned*)d_ws;                 // n*64 (bf16x2)
  unsigned* agg1    = pooled1 + (size_t)n * 64;        // n*64
  unsigned* h1      = agg1 + (size_t)n * 64;           // n*32
  unsigned* pooled2 = h1 + (size_t)n * 32;             // n*32
  unsigned* ebuf    = pooled2 + (size_t)n * 32;        // NB*BIN_CAP
  unsigned* packW   = ebuf + (size_t)NB * BIN_CAP;     // 88*512
  unsigned* binCursor = packW + 88 * 512;              // NB
  float* outp = (float*)d_out;

  // ---- front ----
  hipMemsetAsync(binCursor, 0, (size_t)NB * sizeof(unsigned), stream);
  pack_w<<<88, 64, 0, stream>>>(W_pool1, W_self1, W_neigh1,
                                W_pool2, W_self2, W_neigh2, packW);
  fused_front<<<NSB + GG, 512, 0, stream>>>(
      src, dst, binCursor, ebuf, nE, NB, NSB,
      x, packW, b_pool1, pooled1, n);

  // ---- layer 1 (+ fused pool2) ----
  agg_sort<64><<<NB, 512, 0, stream>>>(ebuf, binCursor, pooled1, agg1, n);
  gemm_dual1_pool2<<<GG, 256, 0, stream>>>(
      x, agg1, packW, b1, b_pool2, h1, pooled2, n);

  // ---- layer 2 (+ head) ----
  agg_gemm_head<32, 64, 72, 80><<<NB, 512, 0, stream>>>(
      ebuf, binCursor, pooled2, h1, packW, b2, W_out, b_out, outp, n);
}

// Round 17
// 179.534 us; speedup vs baseline: 1.0677x; 1.0677x over previous
//
#include <hip/hip_runtime.h>

// GraphSAGE (pool aggregator), 2 layers + linear head.
// N=100000, E=1600000, IN=128, H=64, C=2.
// GEMMs: bf16 MFMA (16x16x32), weights split W_hi+W_lo (two MFMA passes).
// Front: 512-thread blocks — scatter + pool1 GEMM. Scatter counting-sorts
// its 8192 edges by bin IN LDS, then burst-writes each bin's run with
// 16-lane groups (1-2 lines/run vs 1 line/edge: ~7x fewer store
// transactions). Runs line-padded with sentinels (agg skips them).
// Aggregation: per-bin counting sort + 4-deep register max. Layer 1 dual
// GEMM + in-LDS pool2; layer 2 agg fused with dual GEMM + head.
// All maxes order-invariant -> deterministic output.

#define BIN_CAP 4864
#define MAX_BINS 1024
#define SCHUNK 8192
#define SENTINEL 0xFFFFFFFFu

typedef __attribute__((ext_vector_type(8))) short bf16x8;
typedef __attribute__((ext_vector_type(4))) float f32x4;

union FU { uint4 u; bf16x8 v; };

__device__ __forceinline__ unsigned bf16rne(float f) {
  const unsigned u = __float_as_uint(f);
  return (u + 0x7FFFu + ((u >> 16) & 1u)) >> 16;
}

__device__ __forceinline__ unsigned umax_(unsigned a, unsigned b) {
  return a > b ? a : b;
}

// ------- weight pack (fragment-ordered W_hi/W_lo) + binCursor zeroing ------
__global__ __launch_bounds__(64) void pack_w(
    const float* __restrict__ Wp1, const float* __restrict__ Ws1,
    const float* __restrict__ Wn1, const float* __restrict__ Wp2,
    const float* __restrict__ Ws2, const float* __restrict__ Wn2,
    unsigned* __restrict__ packW, unsigned* __restrict__ binCursor, int nb) {
  const int b = blockIdx.x, l = threadIdx.x;
  if (b >= 88) {  // zero binCursor
    for (int i = l; i < nb; i += 64) binCursor[i] = 0u;
    return;
  }
  const float* W; int N, base, fi;
  if (b < 32)      { W = Wp1; N = 128; base = 0;  fi = b; }
  else if (b < 48) { W = Ws1; N = 64;  base = 32; fi = b - 32; }
  else if (b < 64) { W = Wn1; N = 64;  base = 48; fi = b - 48; }
  else if (b < 72) { W = Wp2; N = 64;  base = 64; fi = b - 64; }
  else if (b < 80) { W = Ws2; N = 64;  base = 72; fi = b - 72; }
  else             { W = Wn2; N = 64;  base = 80; fi = b - 80; }
  const int NT = N / 16;
  const int ks = fi / NT, nt = fi % NT;
  const int col = nt * 16 + (l & 15);
  unsigned hs[8], ls[8];
#pragma unroll
  for (int i = 0; i < 8; ++i) {
    const int k = ks * 32 + (l >> 4) * 8 + i;
    const float w = W[(size_t)k * N + col];
    const unsigned h = bf16rne(w);
    const float r = w - __uint_as_float(h << 16);
    hs[i] = h; ls[i] = bf16rne(r);
  }
  uint4 hw, lw;
  hw.x = hs[0] | (hs[1] << 16); hw.y = hs[2] | (hs[3] << 16);
  hw.z = hs[4] | (hs[5] << 16); hw.w = hs[6] | (hs[7] << 16);
  lw.x = ls[0] | (ls[1] << 16); lw.y = ls[2] | (ls[3] << 16);
  lw.z = ls[4] | (ls[5] << 16); lw.w = ls[6] | (ls[7] << 16);
  unsigned* p = packW + (size_t)(base + fi) * 512 + l * 4;
  *(uint4*)p = hw;
  *(uint4*)(p + 256) = lw;
}

// ---------------- 2-row MFMA pass (256-thread GEMMs) ----------------
template <int DIN, int DOUT, bool AF32>
__device__ __forceinline__ void mfma_pass(
    const void* __restrict__ P, const unsigned* __restrict__ packW,
    int fragBase, int ra0, int ra1, int l, f32x4* acc0, f32x4* acc1) {
  constexpr int KS = DIN / 32, NT = DOUT / 16;
  const int lk = l >> 4;
#pragma unroll
  for (int ks = 0; ks < KS; ++ks) {
    FU a0, a1;
    if (AF32) {
      const float* p0 = (const float*)P + (size_t)ra0 * DIN + ks * 32 + lk * 8;
      const float* p1 = (const float*)P + (size_t)ra1 * DIN + ks * 32 + lk * 8;
      const float4 f00 = *(const float4*)p0, f01 = *(const float4*)(p0 + 4);
      const float4 f10 = *(const float4*)p1, f11 = *(const float4*)(p1 + 4);
      a0.u.x = bf16rne(f00.x) | (bf16rne(f00.y) << 16);
      a0.u.y = bf16rne(f00.z) | (bf16rne(f00.w) << 16);
      a0.u.z = bf16rne(f01.x) | (bf16rne(f01.y) << 16);
      a0.u.w = bf16rne(f01.z) | (bf16rne(f01.w) << 16);
      a1.u.x = bf16rne(f10.x) | (bf16rne(f10.y) << 16);
      a1.u.y = bf16rne(f10.z) | (bf16rne(f10.w) << 16);
      a1.u.z = bf16rne(f11.x) | (bf16rne(f11.y) << 16);
      a1.u.w = bf16rne(f11.z) | (bf16rne(f11.w) << 16);
    } else {
      a0.u = *(const uint4*)((const unsigned*)P + (size_t)ra0 * (DIN / 2) + ks * 16 + lk * 4);
      a1.u = *(const uint4*)((const unsigned*)P + (size_t)ra1 * (DIN / 2) + ks * 16 + lk * 4);
    }
#pragma unroll
    for (int nt = 0; nt < NT; ++nt) {
      const unsigned* bp = packW + (size_t)(fragBase + ks * NT + nt) * 512 + l * 4;
      FU bh, bl_;
      bh.u = *(const uint4*)bp;
      bl_.u = *(const uint4*)(bp + 256);
      acc0[nt] = __builtin_amdgcn_mfma_f32_16x16x32_bf16(a0.v, bh.v, acc0[nt], 0, 0, 0);
      acc1[nt] = __builtin_amdgcn_mfma_f32_16x16x32_bf16(a1.v, bh.v, acc1[nt], 0, 0, 0);
      acc0[nt] = __builtin_amdgcn_mfma_f32_16x16x32_bf16(a0.v, bl_.v, acc0[nt], 0, 0, 0);
      acc1[nt] = __builtin_amdgcn_mfma_f32_16x16x32_bf16(a1.v, bl_.v, acc1[nt], 0, 0, 0);
    }
  }
}

// pool1 body, 512 threads: 8 waves x 16 rows; out = relu(x@Wp1+b) packed bf16.
__device__ __forceinline__ void pool1_body512(
    int bid, int tid, const float* __restrict__ x,
    const unsigned* __restrict__ packW, const float* __restrict__ bias,
    unsigned* __restrict__ out, int n) {
  const int wv = tid >> 6, l = tid & 63;
  const int lrow = l & 15, lk = l >> 4;
  const int r0 = bid * 128 + wv * 16;
  int ra = r0 + lrow; if (ra >= n) ra = n - 1;
  f32x4 acc[8];
#pragma unroll
  for (int i = 0; i < 8; ++i) acc[i] = f32x4{0.f, 0.f, 0.f, 0.f};
#pragma unroll
  for (int ks = 0; ks < 4; ++ks) {
    FU a;
    const float* p = x + (size_t)ra * 128 + ks * 32 + lk * 8;
    const float4 f0 = *(const float4*)p, f1 = *(const float4*)(p + 4);
    a.u.x = bf16rne(f0.x) | (bf16rne(f0.y) << 16);
    a.u.y = bf16rne(f0.z) | (bf16rne(f0.w) << 16);
    a.u.z = bf16rne(f1.x) | (bf16rne(f1.y) << 16);
    a.u.w = bf16rne(f1.z) | (bf16rne(f1.w) << 16);
#pragma unroll
    for (int nt = 0; nt < 8; ++nt) {
      const unsigned* bp = packW + (size_t)(ks * 8 + nt) * 512 + l * 4;
      FU bh, bl_;
      bh.u = *(const uint4*)bp;
      bl_.u = *(const uint4*)(bp + 256);
      acc[nt] = __builtin_amdgcn_mfma_f32_16x16x32_bf16(a.v, bh.v, acc[nt], 0, 0, 0);
      acc[nt] = __builtin_amdgcn_mfma_f32_16x16x32_bf16(a.v, bl_.v, acc[nt], 0, 0, 0);
    }
  }
#pragma unroll
  for (int nt = 0; nt < 8; ++nt) {
    const float bv = bias[nt * 16 + lrow];
#pragma unroll
    for (int i = 0; i < 4; ++i) {
      float v = fmaxf(acc[nt][i] + bv, 0.f);
      const float vo = __shfl_xor(v, 1);
      const int row = r0 + lk * 4 + i;
      if (!(l & 1) && row < n)
        out[(size_t)row * 64 + nt * 8 + (lrow >> 1)] =
            bf16rne(v) | (bf16rne(vo) << 16);
    }
  }
}

// ---- scatter body (512 threads): LDS counting sort + burst run writes ----
struct ScatterLds {
  int hist[MAX_BINS];     // count, then LDS scatter cursor
  int gbase[MAX_BINS];    // padded global reservation base
  int lstart[MAX_BINS];   // local run start (exclusive scan)
  int scanbuf[512];
  unsigned sortedW[SCHUNK];
};

__device__ __forceinline__ void scatter_body512(
    int bid, int t, ScatterLds* S,
    const int* __restrict__ src, const int* __restrict__ dst,
    unsigned* __restrict__ binCursor, unsigned* __restrict__ ebuf,
    int nE, int nb) {
  const int blockBase = bid * SCHUNK;
  for (int i = t; i < nb; i += 512) S->hist[i] = 0;
  __syncthreads();
  const int lim = (nE - blockBase < SCHUNK) ? (nE - blockBase) : SCHUNK;
  const int* dp = dst + blockBase;
  const int* sp = src + blockBase;
  const int nv = lim >> 2;
  // pass 1: histogram
  for (int v = t; v < nv; v += 512) {
    const int4 d4 = *(const int4*)(dp + v * 4);
    atomicAdd(&S->hist[d4.x >> 7], 1);
    atomicAdd(&S->hist[d4.y >> 7], 1);
    atomicAdd(&S->hist[d4.z >> 7], 1);
    atomicAdd(&S->hist[d4.w >> 7], 1);
  }
  for (int i = (nv << 2) + t; i < lim; i += 512)
    atomicAdd(&S->hist[dp[i] >> 7], 1);
  __syncthreads();
  // block scan (2 bins/thread) -> lstart (exclusive)
  const int v0 = (2 * t < nb) ? S->hist[2 * t] : 0;
  const int v1 = (2 * t + 1 < nb) ? S->hist[2 * t + 1] : 0;
  S->scanbuf[t] = v0 + v1;
  __syncthreads();
#pragma unroll
  for (int ofs = 1; ofs < 512; ofs <<= 1) {
    const int p = (t >= ofs) ? S->scanbuf[t - ofs] : 0;
    __syncthreads();
    S->scanbuf[t] += p;
    __syncthreads();
  }
  const int ex = S->scanbuf[t] - (v0 + v1);
  if (2 * t < nb) S->lstart[2 * t] = ex;
  if (2 * t + 1 < nb) S->lstart[2 * t + 1] = ex + v0;
  __syncthreads();
  // global padded reservation; hist becomes LDS scatter cursor (= lstart)
  for (int i = t; i < nb; i += 512) {
    const int c = S->hist[i];
    int pb = 0;
    if (c) pb = (int)atomicAdd(&binCursor[i], (unsigned)((c + 15) & ~15));
    S->gbase[i] = pb;
    S->hist[i] = S->lstart[i];
  }
  __syncthreads();
  // pass 2: LDS scatter (sort by bin)
  for (int v = t; v < nv; v += 512) {
    const int4 d4 = *(const int4*)(dp + v * 4);
    const int4 s4 = *(const int4*)(sp + v * 4);
    const int dd[4] = {d4.x, d4.y, d4.z, d4.w};
    const int ss[4] = {s4.x, s4.y, s4.z, s4.w};
#pragma unroll
    for (int q = 0; q < 4; ++q) {
      const int pos = atomicAdd(&S->hist[dd[q] >> 7], 1);
      S->sortedW[pos] = ((unsigned)ss[q] << 7) | (unsigned)(dd[q] & 127);
    }
  }
  for (int i = (nv << 2) + t; i < lim; i += 512) {
    const int d = dp[i];
    const int pos = atomicAdd(&S->hist[d >> 7], 1);
    S->sortedW[pos] = ((unsigned)sp[i] << 7) | (unsigned)(d & 127);
  }
  __syncthreads();
  // burst write: 16-lane group per bin, 16-word (64B) line granules,
  // pad with sentinels to the padded reservation.
  const int w = t >> 6, l = t & 63;
  const int g = l >> 4, j0 = l & 15;
  for (int bin = w * 4 + g; bin < nb; bin += 32) {
    const int ls = S->lstart[bin];
    const int cnt = S->hist[bin] - ls;
    if (!cnt) continue;
    const int padded = (cnt + 15) & ~15;
    const int gb = S->gbase[bin];
    unsigned* bp = ebuf + (size_t)bin * BIN_CAP;
    for (int j = j0; j < padded; j += 16) {
      const unsigned v = (j < cnt) ? S->sortedW[ls + j] : SENTINEL;
      const unsigned pos = (unsigned)(gb + j);
      if (pos < BIN_CAP) bp[pos] = v;
    }
  }
}

// ---------------- fused front (512 threads): scatter + pool1 GEMM ----------
__global__ __launch_bounds__(512) void fused_front(
    const int* __restrict__ src, const int* __restrict__ dst,
    unsigned* __restrict__ binCursor, unsigned* __restrict__ ebuf,
    int nE, int nb, int nsb,
    const float* __restrict__ x, const unsigned* __restrict__ packW,
    const float* __restrict__ bias, unsigned* __restrict__ pooled1, int n) {
  __shared__ ScatterLds S;
  if ((int)blockIdx.x < nsb) {
    scatter_body512(blockIdx.x, threadIdx.x, &S,
                    src, dst, binCursor, ebuf, nE, nb);
  } else {
    pool1_body512(blockIdx.x - nsb, threadIdx.x, x, packW, bias, pooled1, n);
  }
}

// ---------------- agg_sort: counting sort (sentinel-skip) + register max ---
template <int POOLW>
__global__ __launch_bounds__(512) void agg_sort(
    const unsigned* __restrict__ ebuf, const unsigned* __restrict__ binCnt,
    const unsigned* __restrict__ pooled, unsigned* __restrict__ agg, int n) {
  __shared__ unsigned sorted[BIN_CAP];
  __shared__ int hist[128];
  __shared__ int scan_[128];
  __shared__ int startv[129];
  __shared__ int cursor[128];
  const int b = blockIdx.x;
  const int t = threadIdx.x;
  unsigned cnt = binCnt[b]; if (cnt > BIN_CAP) cnt = BIN_CAP;
  if (t < 128) hist[t] = 0;
  __syncthreads();
  const unsigned* eb = ebuf + (size_t)b * BIN_CAP;
  for (unsigned i = t; i < cnt; i += 512) {
    const unsigned w = eb[i];
    if (w != SENTINEL) atomicAdd(&hist[w & 127u], 1);
  }
  __syncthreads();
  if (t < 128) scan_[t] = hist[t];
  __syncthreads();
#pragma unroll
  for (int ofs = 1; ofs < 128; ofs <<= 1) {
    int v = 0;
    if (t < 128 && t >= ofs) v = scan_[t - ofs];
    __syncthreads();
    if (t < 128) scan_[t] += v;
    __syncthreads();
  }
  if (t < 128) {
    const int s = scan_[t] - hist[t];
    startv[t] = s;
    cursor[t] = s;
    if (t == 127) startv[128] = scan_[127];
  }
  __syncthreads();
  for (unsigned i = t; i < cnt; i += 512) {
    const unsigned w = eb[i];
    if (w != SENTINEL)
      sorted[atomicAdd(&cursor[w & 127u], 1)] = w >> 7;
  }
  __syncthreads();
  constexpr int LW = (POOLW == 64) ? 64 : 32;
  constexpr int NPROC = 512 / LW;
  const int proc = t / LW;
  const int lw = t % LW;
  const int base = b << 7;
  for (int local = proc; local < 128; local += NPROC) {
    const int node = base + local;
    if (node >= n) continue;
    const int s0 = startv[local], s1 = startv[local + 1];
    unsigned me = 0u, mo = 0u;
    int j = s0;
    for (; j + 4 <= s1; j += 4) {
      const unsigned a0 = sorted[j],     a1 = sorted[j + 1];
      const unsigned a2 = sorted[j + 2], a3 = sorted[j + 3];
      const unsigned v0 = pooled[(size_t)a0 * POOLW + lw];
      const unsigned v1 = pooled[(size_t)a1 * POOLW + lw];
      const unsigned v2 = pooled[(size_t)a2 * POOLW + lw];
      const unsigned v3 = pooled[(size_t)a3 * POOLW + lw];
      me = umax_(umax_(me, v0 << 16),
                 umax_(v1 << 16, umax_(v2 << 16, v3 << 16)));
      mo = umax_(umax_(mo, v0 & 0xFFFF0000u),
                 umax_(v1 & 0xFFFF0000u,
                       umax_(v2 & 0xFFFF0000u, v3 & 0xFFFF0000u)));
    }
    for (; j < s1; ++j) {
      const unsigned v = pooled[(size_t)sorted[j] * POOLW + lw];
      me = umax_(me, v << 16);
      mo = umax_(mo, v & 0xFFFF0000u);
    }
    agg[(size_t)node * POOLW + lw] = (me >> 16) | (mo & 0xFFFF0000u);
  }
}

// ---------------- dual GEMM layer1 + fused pool2 ----------------
__global__ __launch_bounds__(256) void gemm_dual1_pool2(
    const float* __restrict__ x, const unsigned* __restrict__ agg1,
    const unsigned* __restrict__ packW, const float* __restrict__ b1,
    const float* __restrict__ bp2, unsigned* __restrict__ h1,
    unsigned* __restrict__ pooled2, int n) {
  __shared__ unsigned h1s[128 * 36];
  const int t = threadIdx.x;
  const int wave = t >> 6, l = t & 63;
  const int lrow = l & 15, lk = l >> 4;
  const int lr0 = wave * 32;
  const int r0 = blockIdx.x * 128 + lr0;
  int ra0 = r0 + lrow;      if (ra0 >= n) ra0 = n - 1;
  int ra1 = r0 + 16 + lrow; if (ra1 >= n) ra1 = n - 1;
  f32x4 acc0[4], acc1[4];
#pragma unroll
  for (int i = 0; i < 4; ++i) {
    acc0[i] = f32x4{0.f, 0.f, 0.f, 0.f};
    acc1[i] = f32x4{0.f, 0.f, 0.f, 0.f};
  }
  mfma_pass<128, 64, true>(x, packW, 32, ra0, ra1, l, acc0, acc1);
  mfma_pass<128, 64, false>(agg1, packW, 48, ra0, ra1, l, acc0, acc1);
#pragma unroll
  for (int nt = 0; nt < 4; ++nt) {
    const float bv = b1[nt * 16 + lrow];
#pragma unroll
    for (int j = 0; j < 2; ++j) {
      const f32x4 a = j ? acc1[nt] : acc0[nt];
#pragma unroll
      for (int i = 0; i < 4; ++i) {
        float v = fmaxf(a[i] + bv, 0.f);
        const float vo = __shfl_xor(v, 1);
        if (!(l & 1)) {
          const int rl = lr0 + j * 16 + lk * 4 + i;
          const unsigned w = bf16rne(v) | (bf16rne(vo) << 16);
          h1s[rl * 36 + nt * 8 + (lrow >> 1)] = w;
          const int row = blockIdx.x * 128 + rl;
          if (row < n) h1[(size_t)row * 32 + nt * 8 + (lrow >> 1)] = w;
        }
      }
    }
  }
  __syncthreads();
#pragma unroll
  for (int i = 0; i < 4; ++i) {
    acc0[i] = f32x4{0.f, 0.f, 0.f, 0.f};
    acc1[i] = f32x4{0.f, 0.f, 0.f, 0.f};
  }
#pragma unroll
  for (int ks = 0; ks < 2; ++ks) {
    FU a0, a1;
    a0.u = *(const uint4*)&h1s[(lr0 + lrow) * 36 + ks * 16 + lk * 4];
    a1.u = *(const uint4*)&h1s[(lr0 + 16 + lrow) * 36 + ks * 16 + lk * 4];
#pragma unroll
    for (int nt = 0; nt < 4; ++nt) {
      const unsigned* bp = packW + (size_t)(64 + ks * 4 + nt) * 512 + l * 4;
      FU bh, bl_;
      bh.u = *(const uint4*)bp;
      bl_.u = *(const uint4*)(bp + 256);
      acc0[nt] = __builtin_amdgcn_mfma_f32_16x16x32_bf16(a0.v, bh.v, acc0[nt], 0, 0, 0);
      acc1[nt] = __builtin_amdgcn_mfma_f32_16x16x32_bf16(a1.v, bh.v, acc1[nt], 0, 0, 0);
      acc0[nt] = __builtin_amdgcn_mfma_f32_16x16x32_bf16(a0.v, bl_.v, acc0[nt], 0, 0, 0);
      acc1[nt] = __builtin_amdgcn_mfma_f32_16x16x32_bf16(a1.v, bl_.v, acc1[nt], 0, 0, 0);
    }
  }
#pragma unroll
  for (int nt = 0; nt < 4; ++nt) {
    const float bv = bp2[nt * 16 + lrow];
#pragma unroll
    for (int j = 0; j < 2; ++j) {
      const f32x4 a = j ? acc1[nt] : acc0[nt];
#pragma unroll
      for (int i = 0; i < 4; ++i) {
        float v = fmaxf(a[i] + bv, 0.f);
        const float vo = __shfl_xor(v, 1);
        const int row = r0 + j * 16 + lk * 4 + i;
        if (!(l & 1) && row < n)
          pooled2[(size_t)row * 32 + nt * 8 + (lrow >> 1)] =
              bf16rne(v) | (bf16rne(vo) << 16);
      }
    }
  }
}

// ---------------- fused per-bin aggregation + GEMM + head (layer 2) --------
template <int POOLW, int DIN, int FB0, int FB1>
__global__ __launch_bounds__(512) void agg_gemm_head(
    const unsigned* __restrict__ ebuf, const unsigned* __restrict__ binCnt,
    const unsigned* __restrict__ pooled, const unsigned* __restrict__ A,
    const unsigned* __restrict__ packW, const float* __restrict__ bias,
    const float* __restrict__ Wout, const float* __restrict__ bout,
    float* __restrict__ outf, int n) {
  constexpr int STR = POOLW + 4;
  __shared__ unsigned sorted[BIN_CAP];
  __shared__ int hist[128];
  __shared__ int scan_[128];
  __shared__ int startv[129];
  __shared__ int cursor[128];
  __shared__ unsigned agg_lds[128 * STR];
  const int b = blockIdx.x;
  const int t = threadIdx.x;
  unsigned cnt = binCnt[b]; if (cnt > BIN_CAP) cnt = BIN_CAP;
  if (t < 128) hist[t] = 0;
  __syncthreads();
  const unsigned* eb = ebuf + (size_t)b * BIN_CAP;
  for (unsigned i = t; i < cnt; i += 512) {
    const unsigned w = eb[i];
    if (w != SENTINEL) atomicAdd(&hist[w & 127u], 1);
  }
  __syncthreads();
  if (t < 128) scan_[t] = hist[t];
  __syncthreads();
#pragma unroll
  for (int ofs = 1; ofs < 128; ofs <<= 1) {
    int v = 0;
    if (t < 128 && t >= ofs) v = scan_[t - ofs];
    __syncthreads();
    if (t < 128) scan_[t] += v;
    __syncthreads();
  }
  if (t < 128) {
    const int s = scan_[t] - hist[t];
    startv[t] = s;
    cursor[t] = s;
    if (t == 127) startv[128] = scan_[127];
  }
  __syncthreads();
  for (unsigned i = t; i < cnt; i += 512) {
    const unsigned w = eb[i];
    if (w != SENTINEL)
      sorted[atomicAdd(&cursor[w & 127u], 1)] = w >> 7;
  }
  __syncthreads();
  {
    constexpr int LW = 32;
    constexpr int NPROC = 512 / LW;
    const int proc = t / LW, lw = t % LW;
    for (int local = proc; local < 128; local += NPROC) {
      const int s0 = startv[local], s1 = startv[local + 1];
      unsigned me = 0u, mo = 0u;
      int j = s0;
      for (; j + 4 <= s1; j += 4) {
        const unsigned a0 = sorted[j],     a1 = sorted[j + 1];
        const unsigned a2 = sorted[j + 2], a3 = sorted[j + 3];
        const unsigned v0 = pooled[(size_t)a0 * POOLW + lw];
        const unsigned v1 = pooled[(size_t)a1 * POOLW + lw];
        const unsigned v2 = pooled[(size_t)a2 * POOLW + lw];
        const unsigned v3 = pooled[(size_t)a3 * POOLW + lw];
        me = umax_(umax_(me, v0 << 16),
                   umax_(v1 << 16, umax_(v2 << 16, v3 << 16)));
        mo = umax_(umax_(mo, v0 & 0xFFFF0000u),
                   umax_(v1 & 0xFFFF0000u,
                         umax_(v2 & 0xFFFF0000u, v3 & 0xFFFF0000u)));
      }
      for (; j < s1; ++j) {
        const unsigned v = pooled[(size_t)sorted[j] * POOLW + lw];
        me = umax_(me, v << 16);
        mo = umax_(mo, v & 0xFFFF0000u);
      }
      agg_lds[local * STR + lw] = (me >> 16) | (mo & 0xFFFF0000u);
    }
  }
  __syncthreads();
  constexpr int KS = DIN / 32, NT = 4;
  const int wv = t >> 6, l = t & 63;
  const int lrow = l & 15, lk = l >> 4;
  const int lr = wv * 16 + lrow;
  const int r0 = b * 128 + wv * 16;
  int ra = r0 + lrow; if (ra >= n) ra = n - 1;
  f32x4 acc[NT];
#pragma unroll
  for (int i = 0; i < NT; ++i) acc[i] = f32x4{0.f, 0.f, 0.f, 0.f};
#pragma unroll
  for (int ks = 0; ks < KS; ++ks) {
    FU a;
    a.u = *(const uint4*)(A + (size_t)ra * (DIN / 2) + ks * 16 + lk * 4);
#pragma unroll
    for (int nt = 0; nt < NT; ++nt) {
      const unsigned* bp = packW + (size_t)(FB0 + ks * NT + nt) * 512 + l * 4;
      FU bh, bl_;
      bh.u = *(const uint4*)bp;
      bl_.u = *(const uint4*)(bp + 256);
      acc[nt] = __builtin_amdgcn_mfma_f32_16x16x32_bf16(a.v, bh.v, acc[nt], 0, 0, 0);
      acc[nt] = __builtin_amdgcn_mfma_f32_16x16x32_bf16(a.v, bl_.v, acc[nt], 0, 0, 0);
    }
  }
#pragma unroll
  for (int ks = 0; ks < KS; ++ks) {
    FU a;
    a.u = *(const uint4*)&agg_lds[lr * STR + ks * 16 + lk * 4];
#pragma unroll
    for (int nt = 0; nt < NT; ++nt) {
      const unsigned* bp = packW + (size_t)(FB1 + ks * NT + nt) * 512 + l * 4;
      FU bh, bl_;
      bh.u = *(const uint4*)bp;
      bl_.u = *(const uint4*)(bp + 256);
      acc[nt] = __builtin_amdgcn_mfma_f32_16x16x32_bf16(a.v, bh.v, acc[nt], 0, 0, 0);
      acc[nt] = __builtin_amdgcn_mfma_f32_16x16x32_bf16(a.v, bl_.v, acc[nt], 0, 0, 0);
    }
  }
  float p0[4] = {0.f, 0.f, 0.f, 0.f}, p1[4] = {0.f, 0.f, 0.f, 0.f};
#pragma unroll
  for (int nt = 0; nt < NT; ++nt) {
    const float bv = bias[nt * 16 + lrow];
    const int c = nt * 16 + lrow;
    const float w0 = Wout[c * 2 + 0], w1 = Wout[c * 2 + 1];
#pragma unroll
    for (int i = 0; i < 4; ++i) {
      const float v = fmaxf(acc[nt][i] + bv, 0.f);
      p0[i] = fmaf(v, w0, p0[i]);
      p1[i] = fmaf(v, w1, p1[i]);
    }
  }
#pragma unroll
  for (int m = 1; m < 16; m <<= 1) {
#pragma unroll
    for (int i = 0; i < 4; ++i) {
      p0[i] += __shfl_xor(p0[i], m);
      p1[i] += __shfl_xor(p1[i], m);
    }
  }
  if (lrow == 0) {
    const float b0 = bout[0], b1v = bout[1];
#pragma unroll
    for (int i = 0; i < 4; ++i) {
      const int row = r0 + lk * 4 + i;
      if (row < n) {
        float2 o; o.x = p0[i] + b0; o.y = p1[i] + b1v;
        *(float2*)(outf + (size_t)row * 2) = o;
      }
    }
  }
}

extern "C" void kernel_launch(void* const* d_in, const int* in_sizes, int n_in,
                              void* d_out, int out_size, void* d_ws, size_t ws_size,
                              hipStream_t stream) {
  const float* x       = (const float*)d_in[0];
  const int*   src     = (const int*)d_in[1];
  const int*   dst     = (const int*)d_in[2];
  const float* W_pool1 = (const float*)d_in[3];
  const float* b_pool1 = (const float*)d_in[4];
  const float* W_self1 = (const float*)d_in[5];
  const float* W_neigh1= (const float*)d_in[6];
  const float* b1      = (const float*)d_in[7];
  const float* W_pool2 = (const float*)d_in[8];
  const float* b_pool2 = (const float*)d_in[9];
  const float* W_self2 = (const float*)d_in[10];
  const float* W_neigh2= (const float*)d_in[11];
  const float* b2      = (const float*)d_in[12];
  const float* W_out   = (const float*)d_in[13];
  const float* b_out   = (const float*)d_in[14];

  const int n  = in_sizes[0] / 128;
  const int nE = in_sizes[1];
  const int NB = (n + 127) >> 7;
  const int NSB = (nE + SCHUNK - 1) / SCHUNK;
  const int GG = (n + 127) / 128;

  // workspace (u32 units):
  unsigned* pooled1 = (unsigned*)d_ws;                 // n*64 (bf16x2)
  unsigned* agg1    = pooled1 + (size_t)n * 64;        // n*64
  unsigned* h1      = agg1 + (size_t)n * 64;           // n*32
  unsigned* pooled2 = h1 + (size_t)n * 32;             // n*32
  unsigned* ebuf    = pooled2 + (size_t)n * 32;        // NB*BIN_CAP
  unsigned* packW   = ebuf + (size_t)NB * BIN_CAP;     // 88*512
  unsigned* binCursor = packW + 88 * 512;              // NB
  float* outp = (float*)d_out;

  // ---- front (pack_w also zeroes binCursor) ----
  pack_w<<<89, 64, 0, stream>>>(W_pool1, W_self1, W_neigh1,
                                W_pool2, W_self2, W_neigh2,
                                packW, binCursor, NB);
  fused_front<<<NSB + GG, 512, 0, stream>>>(
      src, dst, binCursor, ebuf, nE, NB, NSB,
      x, packW, b_pool1, pooled1, n);

  // ---- layer 1 (+ fused pool2) ----
  agg_sort<64><<<NB, 512, 0, stream>>>(ebuf, binCursor, pooled1, agg1, n);
  gemm_dual1_pool2<<<GG, 256, 0, stream>>>(
      x, agg1, packW, b1, b_pool2, h1, pooled2, n);

  // ---- layer 2 (+ head) ----
  agg_gemm_head<32, 64, 72, 80><<<NB, 512, 0, stream>>>(
      ebuf, binCursor, pooled2, h1, packW, b2, W_out, b_out, outp, n);
}